// Round 10
// baseline (554.574 us; speedup 1.0000x reference)
//
#include <hip/hip_runtime.h>

// SparseRNN: out = COO_spmm(rows, cols, vals, inp) + bias
// N = 100000, D = 128, nnz = 6,500,000
//
// Round 18: DIAGNOSTIC, part 2. R17 facts: (1) sort < 124.6us (never in
// top-5 vs 125us gather halves) -- prior "164us invariant" was an artifact
// of mixing profile-pass and graph-pass timings; (2) gather halves run at
// 6.65 TB/s line-demand = m13 copy ceiling -> gather ~250us is a hardware
// floor at bf16; (3) export/import staging is ~free (prologue hides under
// compute). Sort remains the only unexplained component and has NEVER had
// counters. This round: QUARTER the gather (feats 32q..32q+31, 8-lane
// slots = 8 records/wave-instr, uint2 loads, 1 line/record) so all four
// quarters (~63-72us) sit BELOW the sort -> top-5 = local_sort with full
// counters. g0 exports staging; g1-g3 import. Sort kernel byte-identical.
// Accepted cost ~10-30us for guaranteed sort visibility.
// record = val9<<23 | row_local<<17 | col (4 bytes)

#define N_FEAT      128
#define R_TILE      64
#define TILE_SHIFT  6
#define COL_MASK    0x1FFFF
#define TILE_CAP    2048       // >= n_tiles+1 (1564), pow2 for the scan
#define LSORT_CAP   13312      // edges per sort block (53.2 KB slab, 489 blk)
#define REC_CAP     4608       // gather staging (tile mean 4160, +6.9 sigma)
#define SORT_K      (LSORT_CAP / 512)   // 26 edges per thread
#define SORT_P      (SORT_K / 2)        // 13 edge PAIRS per thread
#define EXP_STRIDE  (68 + REC_CAP)      // ints: rbeg[65] + flag + pad, recs@+68

typedef unsigned int uint32;

// ---------------------------------------------------------------- f32 -> bf16
__device__ __forceinline__ unsigned short f2bf(float f) {
    unsigned int u = __float_as_uint(f);
    u = (u + 0x7FFFu + ((u >> 16) & 1u)) >> 16;   // RNE
    return (unsigned short)u;
}

__device__ __forceinline__ uint32 pack_rec(int r, int c, float v) {
    const uint32 qv = __float2uint_rn(v * 511.0f) & 0x1FFu;
    return (qv << 23) | ((uint32)(r & (R_TILE - 1)) << 17) | (uint32)c;
}

// ---------------------------------------------------------------- local sort
// UNCHANGED (control) -- this is the kernel we need counters for.
__global__ __launch_bounds__(512)
void local_sort_kernel(const int* __restrict__ rows,
                       const int* __restrict__ cols,
                       const float* __restrict__ vals, int nnz,
                       uint32* __restrict__ records,
                       int* __restrict__ loc,      // TILE-MAJOR: loc[t][b]
                       int n_tiles, int n_blocks,
                       const float* __restrict__ inp_f,
                       ushort* __restrict__ inpb, int n4) {
    __shared__ uint32 slab[LSORT_CAP];   // 53.2 KB
    __shared__ int    cnt[TILE_CAP];     // 8 KB
    __shared__ int    wsum[8];

    const int b    = blockIdx.x;
    const int e0   = b * LSORT_CAP;
    const int e1   = min(e0 + LSORT_CAP, nnz);
    const int cntE = e1 - e0;
    const int tid  = threadIdx.x;
    const int lane = tid & 63, wv = tid >> 6;

    for (int i = tid; i < TILE_CAP; i += 512) cnt[i] = 0;
    __syncthreads();

    uint32 rec[SORT_K];
    int    til[SORT_K];
#pragma unroll
    for (int k = 0; k < SORT_P; ++k) {
        const int e  = e0 + (k << 10) + (tid << 1);
        const int i0 = k << 1, i1 = i0 + 1;
        til[i0] = -1; til[i1] = -1;
        if (e + 1 < e1) {
            const int2   r2 = *reinterpret_cast<const int2*>(rows + e);
            const int2   c2 = *reinterpret_cast<const int2*>(cols + e);
            const float2 v2 = *reinterpret_cast<const float2*>(vals + e);
            rec[i0] = pack_rec(r2.x, c2.x, v2.x);
            rec[i1] = pack_rec(r2.y, c2.y, v2.y);
            til[i0] = r2.x >> TILE_SHIFT;
            til[i1] = r2.y >> TILE_SHIFT;
            atomicAdd(&cnt[til[i0]], 1);
            atomicAdd(&cnt[til[i1]], 1);
        } else if (e < e1) {
            const int   r = rows[e];
            rec[i0] = pack_rec(r, cols[e], vals[e]);
            til[i0] = r >> TILE_SHIFT;
            atomicAdd(&cnt[til[i0]], 1);
        }
    }
    __syncthreads();

    const int g  = tid << 2;
    int c0 = cnt[g + 0], c1 = cnt[g + 1], c2 = cnt[g + 2], c3 = cnt[g + 3];
    int tsum = c0 + c1 + c2 + c3;
    int v = tsum;
    for (int off = 1; off < 64; off <<= 1) {
        int u = __shfl_up(v, off);
        if (lane >= off) v += u;
    }
    if (lane == 63) wsum[wv] = v;
    __syncthreads();
    int wpre = 0;
    for (int w = 0; w < wv; ++w) wpre += wsum[w];
    const int excl = wpre + v - tsum;
    int p0 = excl, p1 = p0 + c0, p2 = p1 + c1, p3 = p2 + c2;

    if (g + 0 <= n_tiles) loc[(g + 0) * n_blocks + b] = p0;
    if (g + 1 <= n_tiles) loc[(g + 1) * n_blocks + b] = p1;
    if (g + 2 <= n_tiles) loc[(g + 2) * n_blocks + b] = p2;
    if (g + 3 <= n_tiles) loc[(g + 3) * n_blocks + b] = p3;

    cnt[g + 0] = p0; cnt[g + 1] = p1; cnt[g + 2] = p2; cnt[g + 3] = p3;
    __syncthreads();

#pragma unroll
    for (int k = 0; k < SORT_K; ++k) {
        if (til[k] >= 0) {
            const int p = atomicAdd(&cnt[til[k]], 1);
            slab[p] = rec[k];
        }
    }
    __syncthreads();

    uint32* outp = records + (size_t)b * LSORT_CAP;
    const int nq = cntE >> 2;
    for (int i = tid; i < nq; i += 512)
        reinterpret_cast<uint4*>(outp)[i] = reinterpret_cast<uint4*>(slab)[i];
    for (int i = (nq << 2) + tid; i < cntE; i += 512)
        outp[i] = slab[i];

    for (int i = b * 512 + tid; i < n4; i += gridDim.x * 512) {
        float4 f = reinterpret_cast<const float4*>(inp_f)[i];
        ushort4 h;
        h.x = f2bf(f.x); h.y = f2bf(f.y); h.z = f2bf(f.z); h.w = f2bf(f.w);
        reinterpret_cast<ushort4*>(inpb)[i] = h;
    }
}

// ---------------------------------------------------------------- gather
// one block (512 thr = 8 waves) per 64-row tile; QUARTER selects feats
// [Q*32, Q*32+32). 8-lane slots: lane>>3 = record slot (8 records per
// wave instr), lane&7 = feature quad (8 lanes x 8B bf16 = one 64B
// quarter-row = one cache line per record).
// EXPORT (q0): write rbeg+recs to ws. IMPORT (q1-3): coalesced read, no
// prologue.
template <bool BF16, int QUARTER, bool EXPORT, bool IMPORT>
__global__ __launch_bounds__(512)
void gather_kernel(const float* __restrict__ inp,
                   const ushort* __restrict__ inpb,
                   const uint32* __restrict__ records,
                   const int* __restrict__ loc,   // TILE-MAJOR: loc[t][b]
                   int* __restrict__ expw,
                   int n_blocks, int n_tiles,
                   const float* __restrict__ bias,
                   float* __restrict__ out, int n_rows) {
    __shared__ uint32 raw[REC_CAP];     // 18.4 KB (unused in IMPORT)
    __shared__ uint32 recs[REC_CAP];    // 18.4 KB
    __shared__ int    rcnt[R_TILE];
    __shared__ int    rbeg[R_TILE + 1];
    __shared__ int    rcur[R_TILE];
    __shared__ int    wsum[8];
    __shared__ int    s_total;
    __shared__ int    s_flag;

    const int t    = blockIdx.x;
    const int tid  = threadIdx.x;
    const int lane = tid & 63, wv = tid >> 6;

    bool fits;
    int  total;

    if constexpr (!IMPORT) {
        if (tid < R_TILE) rcnt[tid] = 0;

        int s0 = 0, len = 0;
        if (tid < n_blocks) {
            s0  = loc[t * n_blocks + tid];
            len = loc[(t + 1) * n_blocks + tid] - s0;
        }
        int v = len;
        for (int off = 1; off < 64; off <<= 1) {
            int u = __shfl_up(v, off);
            if (lane >= off) v += u;
        }
        if (lane == 63) wsum[wv] = v;
        __syncthreads();
        int wpre = 0;
        for (int w = 0; w < wv; ++w) wpre += wsum[w];
        const int myoff = wpre + v - len;
        if (tid == 511) s_total = myoff + len;
        __syncthreads();
        total = s_total;
        fits  = (total <= REC_CAP);

        if (fits && len > 0) {
            const uint32* src = records + (size_t)tid * LSORT_CAP + s0;
            for (int i = 0; i < len; ++i) {
                uint32 r = src[i];
                raw[myoff + i] = r;
                atomicAdd(&rcnt[(r >> 17) & (R_TILE - 1)], 1);
            }
        }
        __syncthreads();

        if (wv == 0) {
            int c = rcnt[lane];
            int s = c;
            for (int off = 1; off < 64; off <<= 1) {
                int u = __shfl_up(s, off);
                if (lane >= off) s += u;
            }
            rbeg[lane] = s - c;
            rcur[lane] = s - c;
            if (lane == 63) rbeg[R_TILE] = s;
        }
        __syncthreads();

        if (fits) {
            for (int i = tid; i < total; i += blockDim.x) {
                uint32 r = raw[i];
                int p = atomicAdd(&rcur[(r >> 17) & (R_TILE - 1)], 1);
                recs[p] = r;
            }
        }
        __syncthreads();

        if constexpr (EXPORT) {
            int* hdr = expw + (size_t)t * EXP_STRIDE;
            if (tid < 65) hdr[tid] = rbeg[tid];
            if (tid == 65) hdr[65] = fits ? 1 : -1;
            if (fits) {
                uint32* er = reinterpret_cast<uint32*>(hdr + 68);
                const int nt4 = (total + 3) >> 2;
                for (int i = tid; i < nt4; i += 512)
                    reinterpret_cast<uint4*>(er)[i] =
                        reinterpret_cast<uint4*>(recs)[i];
            }
        }
    } else {
        const int* hdr = expw + (size_t)t * EXP_STRIDE;
        if (tid < 65) rbeg[tid] = hdr[tid];
        if (tid == 65) s_flag = hdr[65];
        __syncthreads();
        fits  = (s_flag > 0);
        total = rbeg[R_TILE];
        if (fits) {
            const uint32* er = reinterpret_cast<const uint32*>(hdr + 68);
            const int nt4 = (total + 3) >> 2;
            for (int i = tid; i < nt4; i += 512)
                reinterpret_cast<uint4*>(recs)[i] =
                    reinterpret_cast<const uint4*>(er)[i];
        }
        __syncthreads();
    }

    const float VQ   = 1.0f / 511.0f;
    const int   slot = lane >> 3;    // record slot 0..7
    const int   fo   = lane & 7;     // feature quad: feats Q*32+fo*4 ..+3

#define REC_ACC(r_)                                                            \
    {                                                                          \
        float  vv_ = (float)((r_) >> 23) * VQ;                                 \
        size_t c_  = (size_t)((r_) & COL_MASK) << 7;                           \
        if (BF16) {                                                            \
            uint2 d_ = reinterpret_cast<const uint2*>(inpb + c_ + QUARTER*32)[fo];\
            a0 = fmaf(vv_, __uint_as_float(d_.x << 16),         a0);           \
            a1 = fmaf(vv_, __uint_as_float(d_.x & 0xFFFF0000u), a1);           \
            a2 = fmaf(vv_, __uint_as_float(d_.y << 16),         a2);           \
            a3 = fmaf(vv_, __uint_as_float(d_.y & 0xFFFF0000u), a3);           \
        } else {                                                               \
            float4 A_ = reinterpret_cast<const float4*>(inp + c_ + QUARTER*32)[fo];\
            a0 = fmaf(vv_, A_.x, a0); a1 = fmaf(vv_, A_.y, a1);                \
            a2 = fmaf(vv_, A_.z, a2); a3 = fmaf(vv_, A_.w, a3);                \
        }                                                                      \
    }

    for (int k = 0; k < 8; ++k) {
        const int rl  = wv * 8 + k;       // 8 waves x 8 rows = 64
        const int row = (t << TILE_SHIFT) + rl;
        if (row >= n_rows) break;

        float a0 = 0.f, a1 = 0.f, a2 = 0.f, a3 = 0.f;

        if (fits) {
            const int s = rbeg[rl], e_ = rbeg[rl + 1];
            int i = s + slot;
            // 16 records / iter (2 x 8 slots) = 2 independent loads in
            // flight per lane, 16 lines per wave-iter
            for (; i + 8 < e_; i += 16) {
                { uint32 r_ = recs[i];     REC_ACC(r_) }
                { uint32 r_ = recs[i + 8]; REC_ACC(r_) }
            }
            if (i < e_) { uint32 r_ = recs[i]; REC_ACC(r_) }
        } else {
            // overflow fallback (statistically never): walk all segments
            for (int b2 = 0; b2 < n_blocks; ++b2) {
                const int q0 = loc[t * n_blocks + b2];
                const int q1 = loc[(t + 1) * n_blocks + b2];
                for (int i2 = q0; i2 < q1; ++i2) {
                    uint32 r_ = records[(size_t)b2 * LSORT_CAP + i2];
                    if ((int)((r_ >> 17) & (R_TILE - 1)) == rl && slot == 0) {
                        REC_ACC(r_)
                    }
                }
            }
        }

        // fold the 8 slot partials (butterfly over bits 3,4,5)
        a0 += __shfl_xor(a0,  8); a1 += __shfl_xor(a1,  8);
        a2 += __shfl_xor(a2,  8); a3 += __shfl_xor(a3,  8);
        a0 += __shfl_xor(a0, 16); a1 += __shfl_xor(a1, 16);
        a2 += __shfl_xor(a2, 16); a3 += __shfl_xor(a3, 16);
        a0 += __shfl_xor(a0, 32); a1 += __shfl_xor(a1, 32);
        a2 += __shfl_xor(a2, 32); a3 += __shfl_xor(a3, 32);

        if (slot == 0) {
            const float b_ = bias[row];
            float4* op = reinterpret_cast<float4*>(out + (size_t)row * N_FEAT
                                                   + QUARTER * 32);
            op[fo] = make_float4(a0 + b_, a1 + b_, a2 + b_, a3 + b_);
        }
    }
#undef REC_ACC
}

// ----------------------------------------------------------------
extern "C" void kernel_launch(void* const* d_in, const int* in_sizes, int n_in,
                              void* d_out, int out_size, void* d_ws, size_t ws_size,
                              hipStream_t stream) {
    const float* inp  = (const float*)d_in[0];
    const int*   rows = (const int*)d_in[1];
    const int*   cols = (const int*)d_in[2];
    const float* vals = (const float*)d_in[3];
    const float* bias = (const float*)d_in[4];
    float*       out  = (float*)d_out;

    const int nnz      = in_sizes[1];                        // E + N
    const int n_rows   = in_sizes[4];                        // N
    const int n_inp    = in_sizes[0];                        // N * 128
    const int n_tiles  = (n_rows + R_TILE - 1) / R_TILE;     // 1563
    const int n_blocks = (nnz + LSORT_CAP - 1) / LSORT_CAP;  // 489 (<= 512)

    // workspace layout
    char*   ws  = (char*)d_ws;
    size_t  off = 0;
    uint32* records = (uint32*)(ws + off);
    off += (size_t)n_blocks * LSORT_CAP * sizeof(uint32);
    int*    loc     = (int*)(ws + off);                      // [n_tiles+1][n_blocks]
    off += (size_t)(n_tiles + 1) * n_blocks * sizeof(int);
    off = (off + 255) & ~(size_t)255;
    ushort* inpb    = (ushort*)(ws + off);
    off += (size_t)n_inp * sizeof(ushort);
    const bool use_bf16 = (ws_size >= off);
    off = (off + 255) & ~(size_t)255;
    int*    expw    = (int*)(ws + off);
    off += (size_t)n_tiles * EXP_STRIDE * sizeof(int);
    const bool use_exp = (ws_size >= off);
    const int  n4 = use_bf16 ? (n_inp / 4) : 0;

    local_sort_kernel<<<n_blocks, 512, 0, stream>>>(rows, cols, vals, nnz,
                                                    records, loc, n_tiles,
                                                    n_blocks, inp, inpb, n4);
#define LAUNCH_Q(BF, Q, EXP, IMP)                                              \
    gather_kernel<BF, Q, EXP, IMP><<<n_tiles, 512, 0, stream>>>(               \
        inp, inpb, records, loc, expw, n_blocks, n_tiles, bias, out, n_rows);

    if (use_bf16) {
        if (use_exp) {
            LAUNCH_Q(true, 0, true,  false)
            LAUNCH_Q(true, 1, false, true )
            LAUNCH_Q(true, 2, false, true )
            LAUNCH_Q(true, 3, false, true )
        } else {
            LAUNCH_Q(true, 0, false, false)
            LAUNCH_Q(true, 1, false, false)
            LAUNCH_Q(true, 2, false, false)
            LAUNCH_Q(true, 3, false, false)
        }
    } else {
        if (use_exp) {
            LAUNCH_Q(false, 0, true,  false)
            LAUNCH_Q(false, 1, false, true )
            LAUNCH_Q(false, 2, false, true )
            LAUNCH_Q(false, 3, false, true )
        } else {
            LAUNCH_Q(false, 0, false, false)
            LAUNCH_Q(false, 1, false, false)
            LAUNCH_Q(false, 2, false, false)
            LAUNCH_Q(false, 3, false, false)
        }
    }
#undef LAUNCH_Q
}

// Round 12
// 416.364 us; speedup vs baseline: 1.3319x; 1.3319x over previous
//
#include <hip/hip_runtime.h>

// SparseRNN: out = COO_spmm(rows, cols, vals, inp) + bias
// N = 100000, D = 128, nnz = 6,500,000
//
// Round 20 = Round 19 resubmit (R19 bench died with "MI355X container
// failed twice" = broker/infra error, same as R9/R10 which cleared on an
// unchanged resubmit). Audit: slab-free stores bounded by scan totals
// (p < LSORT_CAP always); LDS 8.3KB; uniform barriers; no graph-capture
// violations. Resubmitting byte-identical.
//
// R19 theory: gather FROZEN at R17's two halves (line-rate table proved
// they sit at the ~105k lines/us per-CU line-processing ceiling; fp8 fails
// the error budget). Sort: the one untested lever across all variants was
// the 53-61KB LDS slab chain (2 blocks/CU). SLAB-FREE sort: records placed
// DIRECTLY to global via LDS cursor atomics (scattered f&f 4B stores,
// ~8.5-record segments L2-write-combine). LDS 61.4 -> 8.3KB (~6 blocks/CU);
// removes 1 barrier + LDS write+read pass + streamout.
// record = val9<<23 | row_local<<17 | col (4 bytes)

#define N_FEAT      128
#define R_TILE      64
#define TILE_SHIFT  6
#define COL_MASK    0x1FFFF
#define TILE_CAP    2048       // >= n_tiles+1 (1564), pow2 for the scan
#define LSORT_CAP   13312      // edges per sort block (489 blk)
#define REC_CAP     4608       // gather staging (tile mean 4160, +6.9 sigma)
#define SORT_K      (LSORT_CAP / 512)   // 26 edges per thread
#define SORT_P      (SORT_K / 2)        // 13 edge PAIRS per thread
#define EXP_STRIDE  (68 + REC_CAP)      // ints: rbeg[65] + flag + pad, recs@+68

typedef unsigned int uint32;

// ---------------------------------------------------------------- f32 -> bf16
__device__ __forceinline__ unsigned short f2bf(float f) {
    unsigned int u = __float_as_uint(f);
    u = (u + 0x7FFFu + ((u >> 16) & 1u)) >> 16;   // RNE
    return (unsigned short)u;
}

__device__ __forceinline__ uint32 pack_rec(int r, int c, float v) {
    const uint32 qv = __float2uint_rn(v * 511.0f) & 0x1FFu;
    return (qv << 23) | ((uint32)(r & (R_TILE - 1)) << 17) | (uint32)c;
}

// ---------------------------------------------------------------- local sort
// SLAB-FREE: histogram + scan in LDS (8.3KB total), records stored
// straight to their final global positions (scattered 4B, fire-and-forget).
__global__ __launch_bounds__(512)
void local_sort_kernel(const int* __restrict__ rows,
                       const int* __restrict__ cols,
                       const float* __restrict__ vals, int nnz,
                       uint32* __restrict__ records,
                       int* __restrict__ loc,      // TILE-MAJOR: loc[t][b]
                       int n_tiles, int n_blocks,
                       const float* __restrict__ inp_f,
                       ushort* __restrict__ inpb, int n4) {
    __shared__ int cnt[TILE_CAP];     // 8 KB (counts -> excl offsets -> cursors)
    __shared__ int wsum[8];

    const int b    = blockIdx.x;
    const int e0   = b * LSORT_CAP;
    const int e1   = min(e0 + LSORT_CAP, nnz);
    const int tid  = threadIdx.x;
    const int lane = tid & 63, wv = tid >> 6;

    for (int i = tid; i < TILE_CAP; i += 512) cnt[i] = 0;
    __syncthreads();

    // single pass: edge PAIRS -> registers, fused histogram
    uint32 rec[SORT_K];
    int    til[SORT_K];
#pragma unroll
    for (int k = 0; k < SORT_P; ++k) {
        const int e  = e0 + (k << 10) + (tid << 1);
        const int i0 = k << 1, i1 = i0 + 1;
        til[i0] = -1; til[i1] = -1;
        if (e + 1 < e1) {
            const int2   r2 = *reinterpret_cast<const int2*>(rows + e);
            const int2   c2 = *reinterpret_cast<const int2*>(cols + e);
            const float2 v2 = *reinterpret_cast<const float2*>(vals + e);
            rec[i0] = pack_rec(r2.x, c2.x, v2.x);
            rec[i1] = pack_rec(r2.y, c2.y, v2.y);
            til[i0] = r2.x >> TILE_SHIFT;
            til[i1] = r2.y >> TILE_SHIFT;
            atomicAdd(&cnt[til[i0]], 1);
            atomicAdd(&cnt[til[i1]], 1);
        } else if (e < e1) {
            const int   r = rows[e];
            rec[i0] = pack_rec(r, cols[e], vals[e]);
            til[i0] = r >> TILE_SHIFT;
            atomicAdd(&cnt[til[i0]], 1);
        }
    }
    __syncthreads();

    // parallel exclusive scan of 2048 counts (4/thread + shuffle block-scan)
    const int g  = tid << 2;
    int c0 = cnt[g + 0], c1 = cnt[g + 1], c2 = cnt[g + 2], c3 = cnt[g + 3];
    int tsum = c0 + c1 + c2 + c3;
    int v = tsum;
    for (int off = 1; off < 64; off <<= 1) {
        int u = __shfl_up(v, off);
        if (lane >= off) v += u;
    }
    if (lane == 63) wsum[wv] = v;
    __syncthreads();
    int wpre = 0;
    for (int w = 0; w < wv; ++w) wpre += wsum[w];
    const int excl = wpre + v - tsum;
    int p0 = excl, p1 = p0 + c0, p2 = p1 + c1, p3 = p2 + c2;

    // write loc column b, tile-major (scattered 4B, disjoint, f&f)
    if (g + 0 <= n_tiles) loc[(g + 0) * n_blocks + b] = p0;
    if (g + 1 <= n_tiles) loc[(g + 1) * n_blocks + b] = p1;
    if (g + 2 <= n_tiles) loc[(g + 2) * n_blocks + b] = p2;
    if (g + 3 <= n_tiles) loc[(g + 3) * n_blocks + b] = p3;

    // each thread owns cnt[g..g+3] exclusively -> overwrite with cursors
    cnt[g + 0] = p0; cnt[g + 1] = p1; cnt[g + 2] = p2; cnt[g + 3] = p3;
    __syncthreads();

    // place records DIRECTLY to global final positions (no slab, no
    // streamout): LDS cursor atomic -> scattered 4B store, fire-and-forget.
    uint32* outp = records + (size_t)b * LSORT_CAP;
#pragma unroll
    for (int k = 0; k < SORT_K; ++k) {
        if (til[k] >= 0) {
            const int p = atomicAdd(&cnt[til[k]], 1);
            outp[p] = rec[k];
        }
    }

    // fused bf16 convert of inp (independent streaming tail)
    for (int i = b * 512 + tid; i < n4; i += gridDim.x * 512) {
        float4 f = reinterpret_cast<const float4*>(inp_f)[i];
        ushort4 h;
        h.x = f2bf(f.x); h.y = f2bf(f.y); h.z = f2bf(f.z); h.w = f2bf(f.w);
        reinterpret_cast<ushort4*>(inpb)[i] = h;
    }
}

// ---------------------------------------------------------------- gather
// FROZEN R17 structure (two feature halves at the per-CU line-processing
// ceiling, ~125us each). one block (512 thr = 8 waves) per 64-row tile;
// HALF selects feats [HALF*64, HALF*64+64). quarter-wave on half-rows:
// lane>>4 = record slot (4 records/wave instr), lane&15 = feature quad
// (16 lanes x 8B bf16 = one 128B half-row). g0 EXPORTs staging; g1 IMPORTs.
template <bool BF16, int HALF, bool EXPORT, bool IMPORT>
__global__ __launch_bounds__(512)
void gather_kernel(const float* __restrict__ inp,
                   const ushort* __restrict__ inpb,
                   const uint32* __restrict__ records,
                   const int* __restrict__ loc,   // TILE-MAJOR: loc[t][b]
                   int* __restrict__ expw,
                   int n_blocks, int n_tiles,
                   const float* __restrict__ bias,
                   float* __restrict__ out, int n_rows) {
    __shared__ uint32 raw[REC_CAP];     // 18.4 KB (unused in IMPORT)
    __shared__ uint32 recs[REC_CAP];    // 18.4 KB
    __shared__ int    rcnt[R_TILE];
    __shared__ int    rbeg[R_TILE + 1];
    __shared__ int    rcur[R_TILE];
    __shared__ int    wsum[8];
    __shared__ int    s_total;
    __shared__ int    s_flag;

    const int t    = blockIdx.x;
    const int tid  = threadIdx.x;
    const int lane = tid & 63, wv = tid >> 6;

    bool fits;
    int  total;

    if constexpr (!IMPORT) {
        if (tid < R_TILE) rcnt[tid] = 0;

        int s0 = 0, len = 0;
        if (tid < n_blocks) {
            s0  = loc[t * n_blocks + tid];
            len = loc[(t + 1) * n_blocks + tid] - s0;
        }
        int v = len;
        for (int off = 1; off < 64; off <<= 1) {
            int u = __shfl_up(v, off);
            if (lane >= off) v += u;
        }
        if (lane == 63) wsum[wv] = v;
        __syncthreads();
        int wpre = 0;
        for (int w = 0; w < wv; ++w) wpre += wsum[w];
        const int myoff = wpre + v - len;
        if (tid == 511) s_total = myoff + len;
        __syncthreads();
        total = s_total;
        fits  = (total <= REC_CAP);

        if (fits && len > 0) {
            const uint32* src = records + (size_t)tid * LSORT_CAP + s0;
            for (int i = 0; i < len; ++i) {
                uint32 r = src[i];
                raw[myoff + i] = r;
                atomicAdd(&rcnt[(r >> 17) & (R_TILE - 1)], 1);
            }
        }
        __syncthreads();

        if (wv == 0) {
            int c = rcnt[lane];
            int s = c;
            for (int off = 1; off < 64; off <<= 1) {
                int u = __shfl_up(s, off);
                if (lane >= off) s += u;
            }
            rbeg[lane] = s - c;
            rcur[lane] = s - c;
            if (lane == 63) rbeg[R_TILE] = s;
        }
        __syncthreads();

        if (fits) {
            for (int i = tid; i < total; i += blockDim.x) {
                uint32 r = raw[i];
                int p = atomicAdd(&rcur[(r >> 17) & (R_TILE - 1)], 1);
                recs[p] = r;
            }
        }
        __syncthreads();

        if constexpr (EXPORT) {
            int* hdr = expw + (size_t)t * EXP_STRIDE;
            if (tid < 65) hdr[tid] = rbeg[tid];
            if (tid == 65) hdr[65] = fits ? 1 : -1;
            if (fits) {
                uint32* er = reinterpret_cast<uint32*>(hdr + 68);
                const int nt4 = (total + 3) >> 2;
                for (int i = tid; i < nt4; i += 512)
                    reinterpret_cast<uint4*>(er)[i] =
                        reinterpret_cast<uint4*>(recs)[i];
            }
        }
    } else {
        const int* hdr = expw + (size_t)t * EXP_STRIDE;
        if (tid < 65) rbeg[tid] = hdr[tid];
        if (tid == 65) s_flag = hdr[65];
        __syncthreads();
        fits  = (s_flag > 0);
        total = rbeg[R_TILE];
        if (fits) {
            const uint32* er = reinterpret_cast<const uint32*>(hdr + 68);
            const int nt4 = (total + 3) >> 2;
            for (int i = tid; i < nt4; i += 512)
                reinterpret_cast<uint4*>(recs)[i] =
                    reinterpret_cast<const uint4*>(er)[i];
        }
        __syncthreads();
    }

    const float VQ = 1.0f / 511.0f;
    const int   q  = lane >> 4;      // record slot 0..3
    const int   fq = lane & 15;      // feature quad: feats HALF*64+fq*4 ..+3

#define REC_ACC(r_)                                                            \
    {                                                                          \
        float  vv_ = (float)((r_) >> 23) * VQ;                                 \
        size_t c_  = (size_t)((r_) & COL_MASK) << 7;                           \
        if (BF16) {                                                            \
            uint2 d_ = reinterpret_cast<const uint2*>(inpb + c_ + HALF*64)[fq];\
            a0 = fmaf(vv_, __uint_as_float(d_.x << 16),         a0);           \
            a1 = fmaf(vv_, __uint_as_float(d_.x & 0xFFFF0000u), a1);           \
            a2 = fmaf(vv_, __uint_as_float(d_.y << 16),         a2);           \
            a3 = fmaf(vv_, __uint_as_float(d_.y & 0xFFFF0000u), a3);           \
        } else {                                                               \
            float4 A_ = reinterpret_cast<const float4*>(inp + c_ + HALF*64)[fq];\
            a0 = fmaf(vv_, A_.x, a0); a1 = fmaf(vv_, A_.y, a1);                \
            a2 = fmaf(vv_, A_.z, a2); a3 = fmaf(vv_, A_.w, a3);                \
        }                                                                      \
    }

    for (int k = 0; k < 8; ++k) {
        const int rl  = wv * 8 + k;       // 8 waves x 8 rows = 64
        const int row = (t << TILE_SHIFT) + rl;
        if (row >= n_rows) break;

        float a0 = 0.f, a1 = 0.f, a2 = 0.f, a3 = 0.f;

        if (fits) {
            const int s = rbeg[rl], e_ = rbeg[rl + 1];
            int i = s;
            // 16 records / iter = 4 independent loads in flight
            for (; i + 15 < e_; i += 16) {
                { uint32 r_ = recs[i +  0 + q]; REC_ACC(r_) }
                { uint32 r_ = recs[i +  4 + q]; REC_ACC(r_) }
                { uint32 r_ = recs[i +  8 + q]; REC_ACC(r_) }
                { uint32 r_ = recs[i + 12 + q]; REC_ACC(r_) }
            }
            for (; i < e_; i += 4) {
                const int ii_ = i + q;
                if (ii_ < e_) { uint32 r_ = recs[ii_]; REC_ACC(r_) }
            }
        } else {
            // overflow fallback (statistically never): walk all segments
            for (int b2 = 0; b2 < n_blocks; ++b2) {
                const int q0 = loc[t * n_blocks + b2];
                const int q1 = loc[(t + 1) * n_blocks + b2];
                for (int i2 = q0; i2 < q1; ++i2) {
                    uint32 r_ = records[(size_t)b2 * LSORT_CAP + i2];
                    if ((int)((r_ >> 17) & (R_TILE - 1)) == rl && q == 0) {
                        REC_ACC(r_)
                    }
                }
            }
        }

        // fold the 4 quarter-group partials (butterfly over bits 4,5)
        a0 += __shfl_xor(a0, 16); a1 += __shfl_xor(a1, 16);
        a2 += __shfl_xor(a2, 16); a3 += __shfl_xor(a3, 16);
        a0 += __shfl_xor(a0, 32); a1 += __shfl_xor(a1, 32);
        a2 += __shfl_xor(a2, 32); a3 += __shfl_xor(a3, 32);

        if (q == 0) {
            const float b_ = bias[row];
            float4* op = reinterpret_cast<float4*>(out + (size_t)row * N_FEAT
                                                   + HALF * 64);
            op[fq] = make_float4(a0 + b_, a1 + b_, a2 + b_, a3 + b_);
        }
    }
#undef REC_ACC
}

// ----------------------------------------------------------------
extern "C" void kernel_launch(void* const* d_in, const int* in_sizes, int n_in,
                              void* d_out, int out_size, void* d_ws, size_t ws_size,
                              hipStream_t stream) {
    const float* inp  = (const float*)d_in[0];
    const int*   rows = (const int*)d_in[1];
    const int*   cols = (const int*)d_in[2];
    const float* vals = (const float*)d_in[3];
    const float* bias = (const float*)d_in[4];
    float*       out  = (float*)d_out;

    const int nnz      = in_sizes[1];                        // E + N
    const int n_rows   = in_sizes[4];                        // N
    const int n_inp    = in_sizes[0];                        // N * 128
    const int n_tiles  = (n_rows + R_TILE - 1) / R_TILE;     // 1563
    const int n_blocks = (nnz + LSORT_CAP - 1) / LSORT_CAP;  // 489 (<= 512)

    // workspace layout
    char*   ws  = (char*)d_ws;
    size_t  off = 0;
    uint32* records = (uint32*)(ws + off);
    off += (size_t)n_blocks * LSORT_CAP * sizeof(uint32);
    int*    loc     = (int*)(ws + off);                      // [n_tiles+1][n_blocks]
    off += (size_t)(n_tiles + 1) * n_blocks * sizeof(int);
    off = (off + 255) & ~(size_t)255;
    ushort* inpb    = (ushort*)(ws + off);
    off += (size_t)n_inp * sizeof(ushort);
    const bool use_bf16 = (ws_size >= off);
    off = (off + 255) & ~(size_t)255;
    int*    expw    = (int*)(ws + off);
    off += (size_t)n_tiles * EXP_STRIDE * sizeof(int);
    const bool use_exp = (ws_size >= off);
    const int  n4 = use_bf16 ? (n_inp / 4) : 0;

    local_sort_kernel<<<n_blocks, 512, 0, stream>>>(rows, cols, vals, nnz,
                                                    records, loc, n_tiles,
                                                    n_blocks, inp, inpb, n4);
    if (use_bf16) {
        if (use_exp) {
            gather_kernel<true, 0, true,  false><<<n_tiles, 512, 0, stream>>>(
                inp, inpb, records, loc, expw, n_blocks, n_tiles, bias, out, n_rows);
            gather_kernel<true, 1, false, true ><<<n_tiles, 512, 0, stream>>>(
                inp, inpb, records, loc, expw, n_blocks, n_tiles, bias, out, n_rows);
        } else {
            gather_kernel<true, 0, false, false><<<n_tiles, 512, 0, stream>>>(
                inp, inpb, records, loc, expw, n_blocks, n_tiles, bias, out, n_rows);
            gather_kernel<true, 1, false, false><<<n_tiles, 512, 0, stream>>>(
                inp, inpb, records, loc, expw, n_blocks, n_tiles, bias, out, n_rows);
        }
    } else {
        if (use_exp) {
            gather_kernel<false, 0, true,  false><<<n_tiles, 512, 0, stream>>>(
                inp, inpb, records, loc, expw, n_blocks, n_tiles, bias, out, n_rows);
            gather_kernel<false, 1, false, true ><<<n_tiles, 512, 0, stream>>>(
                inp, inpb, records, loc, expw, n_blocks, n_tiles, bias, out, n_rows);
        } else {
            gather_kernel<false, 0, false, false><<<n_tiles, 512, 0, stream>>>(
                inp, inpb, records, loc, expw, n_blocks, n_tiles, bias, out, n_rows);
            gather_kernel<false, 1, false, false><<<n_tiles, 512, 0, stream>>>(
                inp, inpb, records, loc, expw, n_blocks, n_tiles, bias, out, n_rows);
        }
    }
}

// Round 13
// 390.244 us; speedup vs baseline: 1.4211x; 1.0669x over previous
//
#include <hip/hip_runtime.h>

// SparseRNN: out = COO_spmm(rows, cols, vals, inp) + bias
// N = 100000, D = 128, nnz = 6,500,000
//
// Round 21 = byte-identical restore of R17 (best measured: 389.4us).
// R20 post-mortem: slab-free sort REGRESSED 27us (scattered f&f placement
// loses to slab + coalesced streamout); gather halves held at 125.3/125.2
// (control clean). Cross-acquire residue accounting proved noisy (+-35us
// with identical sort: 172/139/68) -> subtraction-based sort theorizing is
// dead. Surviving facts: gather at per-CU line-processing ceiling (~105k
// lines/us, granularity sweep 107k/104k/53k, warm==cold); slab sort best
// of 8 variants, <= ~125us. This round locks the optimum back in; if it
// reproduces within the noise band, next round declares roofline.
// record = val9<<23 | row_local<<17 | col (4 bytes)

#define N_FEAT      128
#define R_TILE      64
#define TILE_SHIFT  6
#define COL_MASK    0x1FFFF
#define TILE_CAP    2048       // >= n_tiles+1 (1564), pow2 for the scan
#define LSORT_CAP   13312      // edges per sort block (53.2 KB slab, 489 blk)
#define REC_CAP     4608       // gather staging (tile mean 4160, +6.9 sigma)
#define SORT_K      (LSORT_CAP / 512)   // 26 edges per thread
#define SORT_P      (SORT_K / 2)        // 13 edge PAIRS per thread
#define EXP_STRIDE  (68 + REC_CAP)      // ints: rbeg[65] + flag + pad, recs@+68

typedef unsigned int uint32;

// ---------------------------------------------------------------- f32 -> bf16
__device__ __forceinline__ unsigned short f2bf(float f) {
    unsigned int u = __float_as_uint(f);
    u = (u + 0x7FFFu + ((u >> 16) & 1u)) >> 16;   // RNE
    return (unsigned short)u;
}

__device__ __forceinline__ uint32 pack_rec(int r, int c, float v) {
    const uint32 qv = __float2uint_rn(v * 511.0f) & 0x1FFu;
    return (qv << 23) | ((uint32)(r & (R_TILE - 1)) << 17) | (uint32)c;
}

// ---------------------------------------------------------------- local sort
// Slab version (best of 8 variants): register-resident single pass,
// LDS slab placement, coalesced streamout, tile-major loc, cvt tail.
__global__ __launch_bounds__(512)
void local_sort_kernel(const int* __restrict__ rows,
                       const int* __restrict__ cols,
                       const float* __restrict__ vals, int nnz,
                       uint32* __restrict__ records,
                       int* __restrict__ loc,      // TILE-MAJOR: loc[t][b]
                       int n_tiles, int n_blocks,
                       const float* __restrict__ inp_f,
                       ushort* __restrict__ inpb, int n4) {
    __shared__ uint32 slab[LSORT_CAP];   // 53.2 KB
    __shared__ int    cnt[TILE_CAP];     // 8 KB
    __shared__ int    wsum[8];

    const int b    = blockIdx.x;
    const int e0   = b * LSORT_CAP;
    const int e1   = min(e0 + LSORT_CAP, nnz);
    const int cntE = e1 - e0;
    const int tid  = threadIdx.x;
    const int lane = tid & 63, wv = tid >> 6;

    for (int i = tid; i < TILE_CAP; i += 512) cnt[i] = 0;
    __syncthreads();

    uint32 rec[SORT_K];
    int    til[SORT_K];
#pragma unroll
    for (int k = 0; k < SORT_P; ++k) {
        const int e  = e0 + (k << 10) + (tid << 1);
        const int i0 = k << 1, i1 = i0 + 1;
        til[i0] = -1; til[i1] = -1;
        if (e + 1 < e1) {
            const int2   r2 = *reinterpret_cast<const int2*>(rows + e);
            const int2   c2 = *reinterpret_cast<const int2*>(cols + e);
            const float2 v2 = *reinterpret_cast<const float2*>(vals + e);
            rec[i0] = pack_rec(r2.x, c2.x, v2.x);
            rec[i1] = pack_rec(r2.y, c2.y, v2.y);
            til[i0] = r2.x >> TILE_SHIFT;
            til[i1] = r2.y >> TILE_SHIFT;
            atomicAdd(&cnt[til[i0]], 1);
            atomicAdd(&cnt[til[i1]], 1);
        } else if (e < e1) {
            const int   r = rows[e];
            rec[i0] = pack_rec(r, cols[e], vals[e]);
            til[i0] = r >> TILE_SHIFT;
            atomicAdd(&cnt[til[i0]], 1);
        }
    }
    __syncthreads();

    const int g  = tid << 2;
    int c0 = cnt[g + 0], c1 = cnt[g + 1], c2 = cnt[g + 2], c3 = cnt[g + 3];
    int tsum = c0 + c1 + c2 + c3;
    int v = tsum;
    for (int off = 1; off < 64; off <<= 1) {
        int u = __shfl_up(v, off);
        if (lane >= off) v += u;
    }
    if (lane == 63) wsum[wv] = v;
    __syncthreads();
    int wpre = 0;
    for (int w = 0; w < wv; ++w) wpre += wsum[w];
    const int excl = wpre + v - tsum;
    int p0 = excl, p1 = p0 + c0, p2 = p1 + c1, p3 = p2 + c2;

    if (g + 0 <= n_tiles) loc[(g + 0) * n_blocks + b] = p0;
    if (g + 1 <= n_tiles) loc[(g + 1) * n_blocks + b] = p1;
    if (g + 2 <= n_tiles) loc[(g + 2) * n_blocks + b] = p2;
    if (g + 3 <= n_tiles) loc[(g + 3) * n_blocks + b] = p3;

    cnt[g + 0] = p0; cnt[g + 1] = p1; cnt[g + 2] = p2; cnt[g + 3] = p3;
    __syncthreads();

#pragma unroll
    for (int k = 0; k < SORT_K; ++k) {
        if (til[k] >= 0) {
            const int p = atomicAdd(&cnt[til[k]], 1);
            slab[p] = rec[k];
        }
    }
    __syncthreads();

    uint32* outp = records + (size_t)b * LSORT_CAP;
    const int nq = cntE >> 2;
    for (int i = tid; i < nq; i += 512)
        reinterpret_cast<uint4*>(outp)[i] = reinterpret_cast<uint4*>(slab)[i];
    for (int i = (nq << 2) + tid; i < cntE; i += 512)
        outp[i] = slab[i];

    for (int i = b * 512 + tid; i < n4; i += gridDim.x * 512) {
        float4 f = reinterpret_cast<const float4*>(inp_f)[i];
        ushort4 h;
        h.x = f2bf(f.x); h.y = f2bf(f.y); h.z = f2bf(f.z); h.w = f2bf(f.w);
        reinterpret_cast<ushort4*>(inpb)[i] = h;
    }
}

// ---------------------------------------------------------------- gather
// Two feature halves at the per-CU line-processing ceiling (~125us each).
// one block (512 thr = 8 waves) per 64-row tile; HALF selects feats
// [HALF*64, HALF*64+64). quarter-wave on half-rows: lane>>4 = record slot
// (4 records/wave instr), lane&15 = feature quad (16 lanes x 8B bf16 =
// one 128B half-row). g0 EXPORTs staging; g1 IMPORTs.
template <bool BF16, int HALF, bool EXPORT, bool IMPORT>
__global__ __launch_bounds__(512)
void gather_kernel(const float* __restrict__ inp,
                   const ushort* __restrict__ inpb,
                   const uint32* __restrict__ records,
                   const int* __restrict__ loc,   // TILE-MAJOR: loc[t][b]
                   int* __restrict__ expw,
                   int n_blocks, int n_tiles,
                   const float* __restrict__ bias,
                   float* __restrict__ out, int n_rows) {
    __shared__ uint32 raw[REC_CAP];     // 18.4 KB (unused in IMPORT)
    __shared__ uint32 recs[REC_CAP];    // 18.4 KB
    __shared__ int    rcnt[R_TILE];
    __shared__ int    rbeg[R_TILE + 1];
    __shared__ int    rcur[R_TILE];
    __shared__ int    wsum[8];
    __shared__ int    s_total;
    __shared__ int    s_flag;

    const int t    = blockIdx.x;
    const int tid  = threadIdx.x;
    const int lane = tid & 63, wv = tid >> 6;

    bool fits;
    int  total;

    if constexpr (!IMPORT) {
        if (tid < R_TILE) rcnt[tid] = 0;

        int s0 = 0, len = 0;
        if (tid < n_blocks) {
            s0  = loc[t * n_blocks + tid];
            len = loc[(t + 1) * n_blocks + tid] - s0;
        }
        int v = len;
        for (int off = 1; off < 64; off <<= 1) {
            int u = __shfl_up(v, off);
            if (lane >= off) v += u;
        }
        if (lane == 63) wsum[wv] = v;
        __syncthreads();
        int wpre = 0;
        for (int w = 0; w < wv; ++w) wpre += wsum[w];
        const int myoff = wpre + v - len;
        if (tid == 511) s_total = myoff + len;
        __syncthreads();
        total = s_total;
        fits  = (total <= REC_CAP);

        if (fits && len > 0) {
            const uint32* src = records + (size_t)tid * LSORT_CAP + s0;
            for (int i = 0; i < len; ++i) {
                uint32 r = src[i];
                raw[myoff + i] = r;
                atomicAdd(&rcnt[(r >> 17) & (R_TILE - 1)], 1);
            }
        }
        __syncthreads();

        if (wv == 0) {
            int c = rcnt[lane];
            int s = c;
            for (int off = 1; off < 64; off <<= 1) {
                int u = __shfl_up(s, off);
                if (lane >= off) s += u;
            }
            rbeg[lane] = s - c;
            rcur[lane] = s - c;
            if (lane == 63) rbeg[R_TILE] = s;
        }
        __syncthreads();

        if (fits) {
            for (int i = tid; i < total; i += blockDim.x) {
                uint32 r = raw[i];
                int p = atomicAdd(&rcur[(r >> 17) & (R_TILE - 1)], 1);
                recs[p] = r;
            }
        }
        __syncthreads();

        if constexpr (EXPORT) {
            int* hdr = expw + (size_t)t * EXP_STRIDE;
            if (tid < 65) hdr[tid] = rbeg[tid];
            if (tid == 65) hdr[65] = fits ? 1 : -1;
            if (fits) {
                uint32* er = reinterpret_cast<uint32*>(hdr + 68);
                const int nt4 = (total + 3) >> 2;
                for (int i = tid; i < nt4; i += 512)
                    reinterpret_cast<uint4*>(er)[i] =
                        reinterpret_cast<uint4*>(recs)[i];
            }
        }
    } else {
        const int* hdr = expw + (size_t)t * EXP_STRIDE;
        if (tid < 65) rbeg[tid] = hdr[tid];
        if (tid == 65) s_flag = hdr[65];
        __syncthreads();
        fits  = (s_flag > 0);
        total = rbeg[R_TILE];
        if (fits) {
            const uint32* er = reinterpret_cast<const uint32*>(hdr + 68);
            const int nt4 = (total + 3) >> 2;
            for (int i = tid; i < nt4; i += 512)
                reinterpret_cast<uint4*>(recs)[i] =
                    reinterpret_cast<const uint4*>(er)[i];
        }
        __syncthreads();
    }

    const float VQ = 1.0f / 511.0f;
    const int   q  = lane >> 4;      // record slot 0..3
    const int   fq = lane & 15;      // feature quad: feats HALF*64+fq*4 ..+3

#define REC_ACC(r_)                                                            \
    {                                                                          \
        float  vv_ = (float)((r_) >> 23) * VQ;                                 \
        size_t c_  = (size_t)((r_) & COL_MASK) << 7;                           \
        if (BF16) {                                                            \
            uint2 d_ = reinterpret_cast<const uint2*>(inpb + c_ + HALF*64)[fq];\
            a0 = fmaf(vv_, __uint_as_float(d_.x << 16),         a0);           \
            a1 = fmaf(vv_, __uint_as_float(d_.x & 0xFFFF0000u), a1);           \
            a2 = fmaf(vv_, __uint_as_float(d_.y << 16),         a2);           \
            a3 = fmaf(vv_, __uint_as_float(d_.y & 0xFFFF0000u), a3);           \
        } else {                                                               \
            float4 A_ = reinterpret_cast<const float4*>(inp + c_ + HALF*64)[fq];\
            a0 = fmaf(vv_, A_.x, a0); a1 = fmaf(vv_, A_.y, a1);                \
            a2 = fmaf(vv_, A_.z, a2); a3 = fmaf(vv_, A_.w, a3);                \
        }                                                                      \
    }

    for (int k = 0; k < 8; ++k) {
        const int rl  = wv * 8 + k;       // 8 waves x 8 rows = 64
        const int row = (t << TILE_SHIFT) + rl;
        if (row >= n_rows) break;

        float a0 = 0.f, a1 = 0.f, a2 = 0.f, a3 = 0.f;

        if (fits) {
            const int s = rbeg[rl], e_ = rbeg[rl + 1];
            int i = s;
            // 16 records / iter = 4 independent loads in flight
            for (; i + 15 < e_; i += 16) {
                { uint32 r_ = recs[i +  0 + q]; REC_ACC(r_) }
                { uint32 r_ = recs[i +  4 + q]; REC_ACC(r_) }
                { uint32 r_ = recs[i +  8 + q]; REC_ACC(r_) }
                { uint32 r_ = recs[i + 12 + q]; REC_ACC(r_) }
            }
            for (; i < e_; i += 4) {
                const int ii_ = i + q;
                if (ii_ < e_) { uint32 r_ = recs[ii_]; REC_ACC(r_) }
            }
        } else {
            // overflow fallback (statistically never): walk all segments
            for (int b2 = 0; b2 < n_blocks; ++b2) {
                const int q0 = loc[t * n_blocks + b2];
                const int q1 = loc[(t + 1) * n_blocks + b2];
                for (int i2 = q0; i2 < q1; ++i2) {
                    uint32 r_ = records[(size_t)b2 * LSORT_CAP + i2];
                    if ((int)((r_ >> 17) & (R_TILE - 1)) == rl && q == 0) {
                        REC_ACC(r_)
                    }
                }
            }
        }

        // fold the 4 quarter-group partials (butterfly over bits 4,5)
        a0 += __shfl_xor(a0, 16); a1 += __shfl_xor(a1, 16);
        a2 += __shfl_xor(a2, 16); a3 += __shfl_xor(a3, 16);
        a0 += __shfl_xor(a0, 32); a1 += __shfl_xor(a1, 32);
        a2 += __shfl_xor(a2, 32); a3 += __shfl_xor(a3, 32);

        if (q == 0) {
            const float b_ = bias[row];
            float4* op = reinterpret_cast<float4*>(out + (size_t)row * N_FEAT
                                                   + HALF * 64);
            op[fq] = make_float4(a0 + b_, a1 + b_, a2 + b_, a3 + b_);
        }
    }
#undef REC_ACC
}

// ----------------------------------------------------------------
extern "C" void kernel_launch(void* const* d_in, const int* in_sizes, int n_in,
                              void* d_out, int out_size, void* d_ws, size_t ws_size,
                              hipStream_t stream) {
    const float* inp  = (const float*)d_in[0];
    const int*   rows = (const int*)d_in[1];
    const int*   cols = (const int*)d_in[2];
    const float* vals = (const float*)d_in[3];
    const float* bias = (const float*)d_in[4];
    float*       out  = (float*)d_out;

    const int nnz      = in_sizes[1];                        // E + N
    const int n_rows   = in_sizes[4];                        // N
    const int n_inp    = in_sizes[0];                        // N * 128
    const int n_tiles  = (n_rows + R_TILE - 1) / R_TILE;     // 1563
    const int n_blocks = (nnz + LSORT_CAP - 1) / LSORT_CAP;  // 489 (<= 512)

    // workspace layout
    char*   ws  = (char*)d_ws;
    size_t  off = 0;
    uint32* records = (uint32*)(ws + off);
    off += (size_t)n_blocks * LSORT_CAP * sizeof(uint32);
    int*    loc     = (int*)(ws + off);                      // [n_tiles+1][n_blocks]
    off += (size_t)(n_tiles + 1) * n_blocks * sizeof(int);
    off = (off + 255) & ~(size_t)255;
    ushort* inpb    = (ushort*)(ws + off);
    off += (size_t)n_inp * sizeof(ushort);
    const bool use_bf16 = (ws_size >= off);
    off = (off + 255) & ~(size_t)255;
    int*    expw    = (int*)(ws + off);
    off += (size_t)n_tiles * EXP_STRIDE * sizeof(int);
    const bool use_exp = (ws_size >= off);
    const int  n4 = use_bf16 ? (n_inp / 4) : 0;

    local_sort_kernel<<<n_blocks, 512, 0, stream>>>(rows, cols, vals, nnz,
                                                    records, loc, n_tiles,
                                                    n_blocks, inp, inpb, n4);
    if (use_bf16) {
        if (use_exp) {
            gather_kernel<true, 0, true,  false><<<n_tiles, 512, 0, stream>>>(
                inp, inpb, records, loc, expw, n_blocks, n_tiles, bias, out, n_rows);
            gather_kernel<true, 1, false, true ><<<n_tiles, 512, 0, stream>>>(
                inp, inpb, records, loc, expw, n_blocks, n_tiles, bias, out, n_rows);
        } else {
            gather_kernel<true, 0, false, false><<<n_tiles, 512, 0, stream>>>(
                inp, inpb, records, loc, expw, n_blocks, n_tiles, bias, out, n_rows);
            gather_kernel<true, 1, false, false><<<n_tiles, 512, 0, stream>>>(
                inp, inpb, records, loc, expw, n_blocks, n_tiles, bias, out, n_rows);
        }
    } else {
        if (use_exp) {
            gather_kernel<false, 0, true,  false><<<n_tiles, 512, 0, stream>>>(
                inp, inpb, records, loc, expw, n_blocks, n_tiles, bias, out, n_rows);
            gather_kernel<false, 1, false, true ><<<n_tiles, 512, 0, stream>>>(
                inp, inpb, records, loc, expw, n_blocks, n_tiles, bias, out, n_rows);
        } else {
            gather_kernel<false, 0, false, false><<<n_tiles, 512, 0, stream>>>(
                inp, inpb, records, loc, expw, n_blocks, n_tiles, bias, out, n_rows);
            gather_kernel<false, 1, false, false><<<n_tiles, 512, 0, stream>>>(
                inp, inpb, records, loc, expw, n_blocks, n_tiles, bias, out, n_rows);
        }
    }
}